// Round 1
// baseline (3046.978 us; speedup 1.0000x reference)
//
#include <hip/hip_runtime.h>
#include <math.h>

#define N_NODES 50000
#define N_EDGES 1600000
#define HEADS 4
#define EMB 16
#define HOUT 64      // HEADS*EMB
#define HIDDEN 256
#define BATCH 1024
#define NEG_SLOPE 0.2f
#define NCHUNK 25    // ceil(50000 / 2048)

__device__ __forceinline__ float lrelu(float x) { return x > 0.f ? x : NEG_SLOPE * x; }

// ---------------- K0: msg_emb = message @ fc_w + fc_b ; c[b] = gat_b . msg_emb[b]
__global__ void k_msgemb(const float* __restrict__ msg, const float* __restrict__ fcw,
                         const float* __restrict__ fcb, const float* __restrict__ gatb,
                         float* __restrict__ msg_emb, float* __restrict__ cvec) {
    __shared__ float mrow[HIDDEN];
    int b = blockIdx.x;
    int j = threadIdx.x;  // 0..63
    for (int k = j; k < HIDDEN; k += 64) mrow[k] = msg[b * HIDDEN + k];
    __syncthreads();
    float acc = fcb[j];
    #pragma unroll 8
    for (int k = 0; k < HIDDEN; k++) acc += mrow[k] * fcw[k * HOUT + j];
    msg_emb[b * HOUT + j] = acc;
    float cv = gatb[j] * acc;
    for (int o = 32; o > 0; o >>= 1) cv += __shfl_down(cv, o);
    if (j == 0) cvec[b] = cv;
}

// ---------------- K1: h = x @ gat_w ; a_s, a_d per (node, head)
__global__ void k_node(const float* __restrict__ x, const float* __restrict__ gatw,
                       const float* __restrict__ atts, const float* __restrict__ attd,
                       float* __restrict__ h, float* __restrict__ a_s, float* __restrict__ a_d) {
    int tid = blockIdx.x * blockDim.x + threadIdx.x;
    int n = tid >> 6;
    int j = tid & 63;
    if (n >= N_NODES) return;
    float4 xv = ((const float4*)x)[n];
    float hv = xv.x * gatw[j] + xv.y * gatw[64 + j] + xv.z * gatw[128 + j] + xv.w * gatw[192 + j];
    h[n * 64 + j] = hv;
    float s = hv * atts[j];
    float d = hv * attd[j];
    for (int o = 8; o > 0; o >>= 1) {
        s += __shfl_down(s, o, 16);
        d += __shfl_down(d, o, 16);
    }
    if ((j & 15) == 0) {
        int head = j >> 4;
        a_s[n * 4 + head] = s;
        a_d[n * 4 + head] = d;
    }
}

// ---------------- K2a: count in-degree
__global__ void k_count(const int* __restrict__ ei, int* __restrict__ cnt) {
    int e = blockIdx.x * blockDim.x + threadIdx.x;
    if (e < N_EDGES) atomicAdd(&cnt[ei[N_EDGES + e]], 1);
}

// ---------------- K2b: exclusive scan (single block of 1024)
__global__ void k_scan(const int* __restrict__ cnt, int* __restrict__ rowptr, int* __restrict__ cursor) {
    __shared__ int wsum[16];
    __shared__ int woff[16];
    __shared__ int s_carry;
    int t = threadIdx.x, lane = t & 63, w = t >> 6;
    if (t == 0) s_carry = 0;
    __syncthreads();
    for (int base = 0; base < N_NODES; base += 1024) {
        int i = base + t;
        int v = (i < N_NODES) ? cnt[i] : 0;
        int sv = v;
        #pragma unroll
        for (int o = 1; o < 64; o <<= 1) {
            int u = __shfl_up(sv, o);
            if (lane >= o) sv += u;
        }
        if (lane == 63) wsum[w] = sv;
        __syncthreads();
        if (t < 16) {
            int xv = wsum[t];
            int sx = xv;
            #pragma unroll
            for (int o = 1; o < 16; o <<= 1) {
                int u = __shfl_up(sx, o, 16);
                if (t >= o) sx += u;
            }
            woff[t] = sx - xv;
            if (t == 15) wsum[15] = sx;  // chunk total
        }
        __syncthreads();
        int excl = s_carry + woff[w] + (sv - v);
        if (i < N_NODES) { rowptr[i] = excl; cursor[i] = excl; }
        int chunk_total = wsum[15];
        __syncthreads();
        if (t == 0) s_carry += chunk_total;
        __syncthreads();
    }
    if (threadIdx.x == 0) rowptr[N_NODES] = s_carry;
}

// ---------------- K2c: scatter src indices into CSR slots
__global__ void k_scatter(const int* __restrict__ ei, int* __restrict__ cursor, int* __restrict__ csr) {
    int e = blockIdx.x * blockDim.x + threadIdx.x;
    if (e < N_EDGES) {
        int d = ei[N_EDGES + e];
        int pos = atomicAdd(&cursor[d], 1);
        csr[pos] = ei[e];
    }
}

// ---------------- K3: per-node softmax + aggregation (one wave per node)
__global__ void k_agg(const int* __restrict__ rowptr, const int* __restrict__ csr,
                      const float* __restrict__ a_s, const float* __restrict__ a_d,
                      const float* __restrict__ h, float* __restrict__ agg) {
    int gid = blockIdx.x * 256 + threadIdx.x;
    int n = gid >> 6;
    int lane = gid & 63;
    if (n >= N_NODES) return;
    int beg = rowptr[n], end = rowptr[n + 1];
    float4 adv = ((const float4*)a_d)[n];
    float m0 = -INFINITY, m1 = -INFINITY, m2 = -INFINITY, m3 = -INFINITY;
    float s0 = 0.f, s1 = 0.f, s2 = 0.f, s3 = 0.f;
    // phase 1: lanes split edges; per-lane online logsumexp for 4 heads
    for (int i = beg + lane; i < end; i += 64) {
        int src = csr[i];
        float4 asv = ((const float4*)a_s)[src];
        float e0 = lrelu(asv.x + adv.x);
        float e1 = lrelu(asv.y + adv.y);
        float e2 = lrelu(asv.z + adv.z);
        float e3 = lrelu(asv.w + adv.w);
        if (e0 > m0) { s0 = s0 * __expf(m0 - e0) + 1.f; m0 = e0; } else s0 += __expf(e0 - m0);
        if (e1 > m1) { s1 = s1 * __expf(m1 - e1) + 1.f; m1 = e1; } else s1 += __expf(e1 - m1);
        if (e2 > m2) { s2 = s2 * __expf(m2 - e2) + 1.f; m2 = e2; } else s2 += __expf(e2 - m2);
        if (e3 > m3) { s3 = s3 * __expf(m3 - e3) + 1.f; m3 = e3; } else s3 += __expf(e3 - m3);
    }
    // butterfly combine across 64 lanes
    #pragma unroll
    for (int o = 1; o < 64; o <<= 1) {
        float mo, so, M, t1, t2;
        mo = __shfl_xor(m0, o); so = __shfl_xor(s0, o); M = fmaxf(m0, mo);
        t1 = (s0 == 0.f) ? 0.f : s0 * __expf(m0 - M); t2 = (so == 0.f) ? 0.f : so * __expf(mo - M);
        m0 = M; s0 = t1 + t2;
        mo = __shfl_xor(m1, o); so = __shfl_xor(s1, o); M = fmaxf(m1, mo);
        t1 = (s1 == 0.f) ? 0.f : s1 * __expf(m1 - M); t2 = (so == 0.f) ? 0.f : so * __expf(mo - M);
        m1 = M; s1 = t1 + t2;
        mo = __shfl_xor(m2, o); so = __shfl_xor(s2, o); M = fmaxf(m2, mo);
        t1 = (s2 == 0.f) ? 0.f : s2 * __expf(m2 - M); t2 = (so == 0.f) ? 0.f : so * __expf(mo - M);
        m2 = M; s2 = t1 + t2;
        mo = __shfl_xor(m3, o); so = __shfl_xor(s3, o); M = fmaxf(m3, mo);
        t1 = (s3 == 0.f) ? 0.f : s3 * __expf(m3 - M); t2 = (so == 0.f) ? 0.f : so * __expf(mo - M);
        m3 = M; s3 = t1 + t2;
    }
    // phase 2: lanes = features; serial over edges, accumulate alpha * h[src]
    int head = lane >> 4;
    float mh = head == 0 ? m0 : head == 1 ? m1 : head == 2 ? m2 : m3;
    float sh = head == 0 ? s0 : head == 1 ? s1 : head == 2 ? s2 : s3;
    float adh = head == 0 ? adv.x : head == 1 ? adv.y : head == 2 ? adv.z : adv.w;
    float inv = 1.f / (sh + 1e-16f);
    float acc = 0.f;
    for (int i = beg; i < end; i++) {
        int src = csr[i];
        float e = lrelu(a_s[src * 4 + head] + adh);
        float alpha = __expf(e - mh) * inv;
        acc += alpha * h[src * 64 + lane];
    }
    agg[n * 64 + lane] = acc;
}

// ---------------- K4: logits = agg @ msg_emb^T + c[b]; write + per-(b,chunk) lse partials
__global__ __launch_bounds__(256, 2) void k_logits(const float* __restrict__ agg,
    const float* __restrict__ msg_emb, const float* __restrict__ cvec,
    float* __restrict__ out, float* __restrict__ pm, float* __restrict__ ps) {
    __shared__ float smsg[8][64];
    __shared__ float sc[8];
    __shared__ float red_m[4], red_s[4];
    int t = threadIdx.x;
    int bg = blockIdx.x;     // 0..127  (8 batch rows each)
    int chunk = blockIdx.y;  // 0..24   (2048 nodes each)
    int nbase = chunk * 2048;
    for (int i = t; i < 512; i += 256) {
        int bi = i >> 6, k = i & 63;
        smsg[bi][k] = msg_emb[(bg * 8 + bi) * 64 + k];
    }
    if (t < 8) sc[t] = cvec[bg * 8 + t];
    __syncthreads();
    float acc[8][8];
    #pragma unroll
    for (int s = 0; s < 8; s++)
        #pragma unroll
        for (int b = 0; b < 8; b++) acc[s][b] = 0.f;
    const float4* aggv = (const float4*)agg;
    #pragma unroll
    for (int k4 = 0; k4 < 16; k4++) {
        float4 aR[8];
        #pragma unroll
        for (int s = 0; s < 8; s++) {
            int n = nbase + s * 256 + t;
            aR[s] = aggv[(size_t)n * 16 + k4];
        }
        #pragma unroll
        for (int b = 0; b < 8; b++) {
            float4 m = ((const float4*)smsg[b])[k4];
            #pragma unroll
            for (int s = 0; s < 8; s++)
                acc[s][b] += aR[s].x * m.x + aR[s].y * m.y + aR[s].z * m.z + aR[s].w * m.w;
        }
    }
    int lane = t & 63, w = t >> 6;
    for (int b = 0; b < 8; b++) {
        int bglob = bg * 8 + b;
        float lm = -INFINITY, lsum = 0.f;
        #pragma unroll
        for (int s = 0; s < 8; s++) {
            int n = nbase + s * 256 + t;
            bool valid = (n < N_NODES);
            float lv = valid ? (acc[s][b] + sc[b]) : -INFINITY;
            if (valid) out[(size_t)bglob * N_NODES + n] = lv;
            if (lv > lm) { lsum = lsum * __expf(lm - lv) + 1.f; lm = lv; }
            else if (lv != -INFINITY) lsum += __expf(lv - lm);
        }
        #pragma unroll
        for (int o = 1; o < 64; o <<= 1) {
            float mo = __shfl_xor(lm, o), so = __shfl_xor(lsum, o);
            float M = fmaxf(lm, mo);
            float t1 = (lsum == 0.f) ? 0.f : lsum * __expf(lm - M);
            float t2 = (so == 0.f) ? 0.f : so * __expf(mo - M);
            lm = M; lsum = t1 + t2;
        }
        if (lane == 0) { red_m[w] = lm; red_s[w] = lsum; }
        __syncthreads();
        if (t == 0) {
            float M = fmaxf(fmaxf(red_m[0], red_m[1]), fmaxf(red_m[2], red_m[3]));
            float S = 0.f;
            for (int i = 0; i < 4; i++) S += (red_s[i] == 0.f) ? 0.f : red_s[i] * __expf(red_m[i] - M);
            pm[bglob * NCHUNK + chunk] = M;
            ps[bglob * NCHUNK + chunk] = S;
        }
        __syncthreads();
    }
}

// ---------------- K5: combine partials per batch row
__global__ void k_rowstats(const float* __restrict__ pm, const float* __restrict__ ps,
                           float* __restrict__ rowm, float* __restrict__ rowls) {
    int b = blockIdx.x * blockDim.x + threadIdx.x;
    if (b >= BATCH) return;
    float M = -INFINITY;
    for (int i = 0; i < NCHUNK; i++) M = fmaxf(M, pm[b * NCHUNK + i]);
    float S = 0.f;
    for (int i = 0; i < NCHUNK; i++) {
        float s = ps[b * NCHUNK + i];
        S += (s == 0.f) ? 0.f : s * __expf(pm[b * NCHUNK + i] - M);
    }
    rowm[b] = M;
    rowls[b] = logf(S);
}

// ---------------- K6: out = logits - (M + log S)
__global__ void k_fix(float* __restrict__ out, const float* __restrict__ rowm,
                      const float* __restrict__ rowls) {
    int idx = blockIdx.x * blockDim.x + threadIdx.x;  // float4 index
    int b = idx / 12500;                              // 50000/4 float4 per row
    float sub = rowm[b] + rowls[b];
    float4 v = ((float4*)out)[idx];
    v.x -= sub; v.y -= sub; v.z -= sub; v.w -= sub;
    ((float4*)out)[idx] = v;
}

extern "C" void kernel_launch(void* const* d_in, const int* in_sizes, int n_in,
                              void* d_out, int out_size, void* d_ws, size_t ws_size,
                              hipStream_t stream) {
    const float* message = (const float*)d_in[0];
    const float* x       = (const float*)d_in[1];
    const int*   ei      = (const int*)d_in[2];
    const float* gat_w   = (const float*)d_in[3];
    const float* att_src = (const float*)d_in[4];
    const float* att_dst = (const float*)d_in[5];
    const float* gat_b   = (const float*)d_in[6];
    const float* fc_w    = (const float*)d_in[7];
    const float* fc_b    = (const float*)d_in[8];
    float* out = (float*)d_out;

    float* ws      = (float*)d_ws;
    float* msg_emb = ws;                       // 1024*64
    float* cvec    = msg_emb + BATCH * HOUT;   // 1024
    float* h       = cvec + BATCH;             // 50000*64
    float* a_s     = h + (size_t)N_NODES * HOUT;     // 50000*4
    float* a_d     = a_s + (size_t)N_NODES * HEADS;  // 50000*4
    float* agg     = a_d + (size_t)N_NODES * HEADS;  // 50000*64
    float* pm      = agg + (size_t)N_NODES * HOUT;   // 1024*25
    float* ps      = pm + BATCH * NCHUNK;
    float* rowm    = ps + BATCH * NCHUNK;      // 1024
    float* rowls   = rowm + BATCH;             // 1024
    int*   cnt     = (int*)(rowls + BATCH);    // 50000
    int*   rowptr  = cnt + N_NODES;            // 50001
    int*   cursor  = rowptr + N_NODES + 1;     // 50000
    int*   csr     = cursor + N_NODES;         // 1600000

    hipMemsetAsync(cnt, 0, N_NODES * sizeof(int), stream);
    k_msgemb<<<BATCH, 64, 0, stream>>>(message, fc_w, fc_b, gat_b, msg_emb, cvec);
    k_node<<<(N_NODES * 64) / 256, 256, 0, stream>>>(x, gat_w, att_src, att_dst, h, a_s, a_d);
    k_count<<<N_EDGES / 256, 256, 0, stream>>>(ei, cnt);
    k_scan<<<1, 1024, 0, stream>>>(cnt, rowptr, cursor);
    k_scatter<<<N_EDGES / 256, 256, 0, stream>>>(ei, cursor, csr);
    k_agg<<<(N_NODES * 64) / 256, 256, 0, stream>>>(rowptr, csr, a_s, a_d, h, agg);
    dim3 g4(128, NCHUNK);
    k_logits<<<g4, 256, 0, stream>>>(agg, msg_emb, cvec, out, pm, ps);
    k_rowstats<<<4, 256, 0, stream>>>(pm, ps, rowm, rowls);
    k_fix<<<(BATCH * N_NODES / 4) / 256, 256, 0, stream>>>(out, rowm, rowls);
}

// Round 2
// 847.127 us; speedup vs baseline: 3.5968x; 3.5968x over previous
//
#include <hip/hip_runtime.h>
#include <math.h>

#define N_NODES 50000
#define N_EDGES 1600000
#define HEADS 4
#define EMB 16
#define HOUT 64      // HEADS*EMB
#define HIDDEN 256
#define BATCH 1024
#define NEG_SLOPE 0.2f
#define ATS 50176    // padded node stride for aggT (64*ATS floats)
#define NCHUNK 49    // ceil(50000 / 1024)

__device__ __forceinline__ float lrelu(float x) { return x > 0.f ? x : NEG_SLOPE * x; }

// ---------------- K0: msg_emb = message @ fc_w + fc_b ; also transposed copy; c[b] = gat_b . msg_emb[b]
__global__ void k_msgemb(const float* __restrict__ msg, const float* __restrict__ fcw,
                         const float* __restrict__ fcb, const float* __restrict__ gatb,
                         float* __restrict__ msg_emb, float* __restrict__ msgT,
                         float* __restrict__ cvec) {
    __shared__ float mrow[HIDDEN];
    int b = blockIdx.x;
    int j = threadIdx.x;  // 0..63
    for (int k = j; k < HIDDEN; k += 64) mrow[k] = msg[b * HIDDEN + k];
    __syncthreads();
    float acc = fcb[j];
    #pragma unroll 8
    for (int k = 0; k < HIDDEN; k++) acc += mrow[k] * fcw[k * HOUT + j];
    msg_emb[b * HOUT + j] = acc;
    msgT[j * BATCH + b] = acc;
    float cv = gatb[j] * acc;
    for (int o = 32; o > 0; o >>= 1) cv += __shfl_down(cv, o);
    if (j == 0) cvec[b] = cv;
}

// ---------------- K1: h = x @ gat_w ; a_s, a_d per (node, head)
__global__ void k_node(const float* __restrict__ x, const float* __restrict__ gatw,
                       const float* __restrict__ atts, const float* __restrict__ attd,
                       float* __restrict__ h, float* __restrict__ a_s, float* __restrict__ a_d) {
    int tid = blockIdx.x * blockDim.x + threadIdx.x;
    int n = tid >> 6;
    int j = tid & 63;
    if (n >= N_NODES) return;
    float4 xv = ((const float4*)x)[n];
    float hv = xv.x * gatw[j] + xv.y * gatw[64 + j] + xv.z * gatw[128 + j] + xv.w * gatw[192 + j];
    h[n * 64 + j] = hv;
    float s = hv * atts[j];
    float d = hv * attd[j];
    for (int o = 8; o > 0; o >>= 1) {
        s += __shfl_down(s, o, 16);
        d += __shfl_down(d, o, 16);
    }
    if ((j & 15) == 0) {
        int head = j >> 4;
        a_s[n * 4 + head] = s;
        a_d[n * 4 + head] = d;
    }
}

// ---------------- K2a: count in-degree
__global__ void k_count(const int* __restrict__ ei, int* __restrict__ cnt) {
    int e = blockIdx.x * blockDim.x + threadIdx.x;
    if (e < N_EDGES) atomicAdd(&cnt[ei[N_EDGES + e]], 1);
}

// ---------------- K2b: exclusive scan (single block of 1024)
__global__ void k_scan(const int* __restrict__ cnt, int* __restrict__ rowptr, int* __restrict__ cursor) {
    __shared__ int wsum[16];
    __shared__ int woff[16];
    __shared__ int s_carry;
    int t = threadIdx.x, lane = t & 63, w = t >> 6;
    if (t == 0) s_carry = 0;
    __syncthreads();
    for (int base = 0; base < N_NODES; base += 1024) {
        int i = base + t;
        int v = (i < N_NODES) ? cnt[i] : 0;
        int sv = v;
        #pragma unroll
        for (int o = 1; o < 64; o <<= 1) {
            int u = __shfl_up(sv, o);
            if (lane >= o) sv += u;
        }
        if (lane == 63) wsum[w] = sv;
        __syncthreads();
        if (t < 16) {
            int xv = wsum[t];
            int sx = xv;
            #pragma unroll
            for (int o = 1; o < 16; o <<= 1) {
                int u = __shfl_up(sx, o, 16);
                if (t >= o) sx += u;
            }
            woff[t] = sx - xv;
            if (t == 15) wsum[15] = sx;  // chunk total
        }
        __syncthreads();
        int excl = s_carry + woff[w] + (sv - v);
        if (i < N_NODES) { rowptr[i] = excl; cursor[i] = excl; }
        int chunk_total = wsum[15];
        __syncthreads();
        if (t == 0) s_carry += chunk_total;
        __syncthreads();
    }
    if (threadIdx.x == 0) rowptr[N_NODES] = s_carry;
}

// ---------------- K2c: scatter src indices into CSR slots
__global__ void k_scatter(const int* __restrict__ ei, int* __restrict__ cursor, int* __restrict__ csr) {
    int e = blockIdx.x * blockDim.x + threadIdx.x;
    if (e < N_EDGES) {
        int d = ei[N_EDGES + e];
        int pos = atomicAdd(&cursor[d], 1);
        csr[pos] = ei[e];
    }
}

// ---------------- K3: per-node softmax + aggregation (one wave per node)
__global__ void k_agg(const int* __restrict__ rowptr, const int* __restrict__ csr,
                      const float* __restrict__ a_s, const float* __restrict__ a_d,
                      const float* __restrict__ h, float* __restrict__ agg) {
    int gid = blockIdx.x * 256 + threadIdx.x;
    int n = gid >> 6;
    int lane = gid & 63;
    if (n >= N_NODES) return;
    int beg = rowptr[n], end = rowptr[n + 1];
    float4 adv = ((const float4*)a_d)[n];
    float m0 = -INFINITY, m1 = -INFINITY, m2 = -INFINITY, m3 = -INFINITY;
    float s0 = 0.f, s1 = 0.f, s2 = 0.f, s3 = 0.f;
    // phase 1: lanes split edges; per-lane online logsumexp for 4 heads
    for (int i = beg + lane; i < end; i += 64) {
        int src = csr[i];
        float4 asv = ((const float4*)a_s)[src];
        float e0 = lrelu(asv.x + adv.x);
        float e1 = lrelu(asv.y + adv.y);
        float e2 = lrelu(asv.z + adv.z);
        float e3 = lrelu(asv.w + adv.w);
        if (e0 > m0) { s0 = s0 * __expf(m0 - e0) + 1.f; m0 = e0; } else s0 += __expf(e0 - m0);
        if (e1 > m1) { s1 = s1 * __expf(m1 - e1) + 1.f; m1 = e1; } else s1 += __expf(e1 - m1);
        if (e2 > m2) { s2 = s2 * __expf(m2 - e2) + 1.f; m2 = e2; } else s2 += __expf(e2 - m2);
        if (e3 > m3) { s3 = s3 * __expf(m3 - e3) + 1.f; m3 = e3; } else s3 += __expf(e3 - m3);
    }
    // butterfly combine across 64 lanes
    #pragma unroll
    for (int o = 1; o < 64; o <<= 1) {
        float mo, so, M, t1, t2;
        mo = __shfl_xor(m0, o); so = __shfl_xor(s0, o); M = fmaxf(m0, mo);
        t1 = (s0 == 0.f) ? 0.f : s0 * __expf(m0 - M); t2 = (so == 0.f) ? 0.f : so * __expf(mo - M);
        m0 = M; s0 = t1 + t2;
        mo = __shfl_xor(m1, o); so = __shfl_xor(s1, o); M = fmaxf(m1, mo);
        t1 = (s1 == 0.f) ? 0.f : s1 * __expf(m1 - M); t2 = (so == 0.f) ? 0.f : so * __expf(mo - M);
        m1 = M; s1 = t1 + t2;
        mo = __shfl_xor(m2, o); so = __shfl_xor(s2, o); M = fmaxf(m2, mo);
        t1 = (s2 == 0.f) ? 0.f : s2 * __expf(m2 - M); t2 = (so == 0.f) ? 0.f : so * __expf(mo - M);
        m2 = M; s2 = t1 + t2;
        mo = __shfl_xor(m3, o); so = __shfl_xor(s3, o); M = fmaxf(m3, mo);
        t1 = (s3 == 0.f) ? 0.f : s3 * __expf(m3 - M); t2 = (so == 0.f) ? 0.f : so * __expf(mo - M);
        m3 = M; s3 = t1 + t2;
    }
    // phase 2: lanes = features; serial over edges, accumulate alpha * h[src]
    int head = lane >> 4;
    float mh = head == 0 ? m0 : head == 1 ? m1 : head == 2 ? m2 : m3;
    float sh = head == 0 ? s0 : head == 1 ? s1 : head == 2 ? s2 : s3;
    float adh = head == 0 ? adv.x : head == 1 ? adv.y : head == 2 ? adv.z : adv.w;
    float inv = 1.f / (sh + 1e-16f);
    float acc = 0.f;
    for (int i = beg; i < end; i++) {
        int src = csr[i];
        float e = lrelu(a_s[src * 4 + head] + adh);
        float alpha = __expf(e - mh) * inv;
        acc += alpha * h[src * 64 + lane];
    }
    agg[n * 64 + lane] = acc;
}

// ---------------- K3b: transpose agg [N][64] -> aggT [64][ATS]
__global__ void k_transpose(const float* __restrict__ agg, float* __restrict__ aggT) {
    __shared__ float tile[64][65];
    int t = threadIdx.x;
    int n0 = blockIdx.x * 64;
    #pragma unroll
    for (int i = 0; i < 16; i++) {
        int idx = i * 256 + t;
        int nl = idx >> 6, f = idx & 63;
        int n = n0 + nl;
        tile[nl][f] = (n < N_NODES) ? agg[(size_t)n * 64 + f] : 0.f;
    }
    __syncthreads();
    #pragma unroll
    for (int i = 0; i < 16; i++) {
        int idx = i * 256 + t;
        int f = idx >> 6, nl = idx & 63;
        int n = n0 + nl;
        if (n < N_NODES) aggT[(size_t)f * ATS + n] = tile[nl][f];
    }
}

// ---------------- K4: logits = aggT^T @ msg_emb^T + c[b]; coalesced, scalar-path B operand
__global__ __launch_bounds__(256, 4) void k_logits(const float* __restrict__ aggT,
    const float* __restrict__ msgT, const float* __restrict__ cvec,
    float* __restrict__ out, float* __restrict__ pm, float* __restrict__ ps) {
    __shared__ float red_m[16][4], red_s[16][4];
    int t = threadIdx.x;
    int bg = blockIdx.x;     // 0..63 : 16 batch rows each
    int chunk = blockIdx.y;  // 0..48 : 1024 nodes each
    int nbase = chunk * 1024;
    float acc[4][16];
    #pragma unroll
    for (int s = 0; s < 4; s++)
        #pragma unroll
        for (int b = 0; b < 16; b++) acc[s][b] = 0.f;

    #pragma unroll 2
    for (int k = 0; k < 64; k++) {
        float aR[4];
        #pragma unroll
        for (int s = 0; s < 4; s++)
            aR[s] = aggT[(size_t)k * ATS + nbase + s * 256 + t];
        const float* mrow = msgT + k * BATCH + bg * 16;  // wave-uniform -> s_load
        #pragma unroll
        for (int b = 0; b < 16; b++) {
            float m = mrow[b];
            #pragma unroll
            for (int s = 0; s < 4; s++) acc[s][b] = fmaf(aR[s], m, acc[s][b]);
        }
    }

    int lane = t & 63, w = t >> 6;
    #pragma unroll
    for (int b = 0; b < 16; b++) {
        int bglob = bg * 16 + b;
        float sc = cvec[bglob];
        float lm = -INFINITY, ls = 0.f;
        #pragma unroll
        for (int s = 0; s < 4; s++) {
            int n = nbase + s * 256 + t;
            if (n < N_NODES) {
                float lv = acc[s][b] + sc;
                out[(size_t)bglob * N_NODES + n] = lv;
                if (lv > lm) { ls = ls * __expf(lm - lv) + 1.f; lm = lv; }
                else ls += __expf(lv - lm);
            }
        }
        #pragma unroll
        for (int o = 1; o < 64; o <<= 1) {
            float mo = __shfl_xor(lm, o), so = __shfl_xor(ls, o);
            float M = fmaxf(lm, mo);
            float t1 = (ls == 0.f) ? 0.f : ls * __expf(lm - M);
            float t2 = (so == 0.f) ? 0.f : so * __expf(mo - M);
            lm = M; ls = t1 + t2;
        }
        if (lane == 0) { red_m[b][w] = lm; red_s[b][w] = ls; }
    }
    __syncthreads();
    if (t < 16) {
        float M = -INFINITY;
        #pragma unroll
        for (int i = 0; i < 4; i++) M = fmaxf(M, red_m[t][i]);
        float S = 0.f;
        #pragma unroll
        for (int i = 0; i < 4; i++)
            S += (red_s[t][i] == 0.f) ? 0.f : red_s[t][i] * __expf(red_m[t][i] - M);
        pm[(bg * 16 + t) * NCHUNK + chunk] = M;
        ps[(bg * 16 + t) * NCHUNK + chunk] = S;
    }
}

// ---------------- K5: combine partials per batch row
__global__ void k_rowstats(const float* __restrict__ pm, const float* __restrict__ ps,
                           float* __restrict__ rowm, float* __restrict__ rowls) {
    int b = blockIdx.x * blockDim.x + threadIdx.x;
    if (b >= BATCH) return;
    float M = -INFINITY;
    for (int i = 0; i < NCHUNK; i++) M = fmaxf(M, pm[b * NCHUNK + i]);
    float S = 0.f;
    for (int i = 0; i < NCHUNK; i++) {
        float s = ps[b * NCHUNK + i];
        S += (s == 0.f) ? 0.f : s * __expf(pm[b * NCHUNK + i] - M);
    }
    rowm[b] = M;
    rowls[b] = logf(S);
}

// ---------------- K6: out = logits - (M + log S)
__global__ void k_fix(float* __restrict__ out, const float* __restrict__ rowm,
                      const float* __restrict__ rowls) {
    int idx = blockIdx.x * blockDim.x + threadIdx.x;  // float4 index
    int b = idx / 12500;                              // 50000/4 float4 per row
    float sub = rowm[b] + rowls[b];
    float4 v = ((float4*)out)[idx];
    v.x -= sub; v.y -= sub; v.z -= sub; v.w -= sub;
    ((float4*)out)[idx] = v;
}

extern "C" void kernel_launch(void* const* d_in, const int* in_sizes, int n_in,
                              void* d_out, int out_size, void* d_ws, size_t ws_size,
                              hipStream_t stream) {
    const float* message = (const float*)d_in[0];
    const float* x       = (const float*)d_in[1];
    const int*   ei      = (const int*)d_in[2];
    const float* gat_w   = (const float*)d_in[3];
    const float* att_src = (const float*)d_in[4];
    const float* att_dst = (const float*)d_in[5];
    const float* gat_b   = (const float*)d_in[6];
    const float* fc_w    = (const float*)d_in[7];
    const float* fc_b    = (const float*)d_in[8];
    float* out = (float*)d_out;

    float* ws      = (float*)d_ws;
    float* msg_emb = ws;                               // 1024*64
    float* msgT    = msg_emb + BATCH * HOUT;           // 64*1024
    float* cvec    = msgT + HOUT * BATCH;              // 1024
    float* a_s     = cvec + BATCH;                     // 50000*4
    float* a_d     = a_s + (size_t)N_NODES * HEADS;    // 50000*4
    float* agg     = a_d + (size_t)N_NODES * HEADS;    // 50000*64
    float* hbuf    = agg + (size_t)N_NODES * HOUT;     // max(50000*64, 64*ATS) floats; h then aggT
    float* aggT    = hbuf;                             // aliases h (h dead after k_agg)
    float* pm      = hbuf + (size_t)HOUT * ATS;        // 1024*49
    float* ps      = pm + BATCH * NCHUNK;              // 1024*49
    float* rowm    = ps + BATCH * NCHUNK;              // 1024
    float* rowls   = rowm + BATCH;                     // 1024
    int*   cnt     = (int*)(rowls + BATCH);            // 50000
    int*   rowptr  = cnt + N_NODES;                    // 50001
    int*   cursor  = rowptr + N_NODES + 1;             // 50000
    int*   csr     = cursor + N_NODES;                 // 1600000

    hipMemsetAsync(cnt, 0, N_NODES * sizeof(int), stream);
    k_msgemb<<<BATCH, 64, 0, stream>>>(message, fc_w, fc_b, gat_b, msg_emb, msgT, cvec);
    k_node<<<(N_NODES * 64 + 255) / 256, 256, 0, stream>>>(x, gat_w, att_src, att_dst, hbuf, a_s, a_d);
    k_count<<<N_EDGES / 256, 256, 0, stream>>>(ei, cnt);
    k_scan<<<1, 1024, 0, stream>>>(cnt, rowptr, cursor);
    k_scatter<<<N_EDGES / 256, 256, 0, stream>>>(ei, cursor, csr);
    k_agg<<<(N_NODES * 64 + 255) / 256, 256, 0, stream>>>(rowptr, csr, a_s, a_d, hbuf, agg);
    k_transpose<<<(N_NODES + 63) / 64, 256, 0, stream>>>(agg, aggT);
    dim3 g4(64, NCHUNK);
    k_logits<<<g4, 256, 0, stream>>>(aggT, msgT, cvec, out, pm, ps);
    k_rowstats<<<4, 256, 0, stream>>>(pm, ps, rowm, rowls);
    k_fix<<<(BATCH * N_NODES / 4 + 255) / 256, 256, 0, stream>>>(out, rowm, rowls);
}

// Round 3
// 685.767 us; speedup vs baseline: 4.4432x; 1.2353x over previous
//
#include <hip/hip_runtime.h>
#include <math.h>

#define N_NODES 50000
#define N_EDGES 1600000
#define HEADS 4
#define EMB 16
#define HOUT 64      // HEADS*EMB
#define HIDDEN 256
#define BATCH 1024
#define NEG_SLOPE 0.2f
#define ATS 50176    // padded node stride for aggT (64*ATS floats)
#define NCHUNK 49    // ceil(50000 / 1024)
#define SCAN_NB 196  // ceil(50000/256)

__device__ __forceinline__ float lrelu(float x) { return x > 0.f ? x : NEG_SLOPE * x; }

// ---------------- K0: msg_emb = message @ fc_w + fc_b ; also transposed copy; c[b] = gat_b . msg_emb[b]
__global__ void k_msgemb(const float* __restrict__ msg, const float* __restrict__ fcw,
                         const float* __restrict__ fcb, const float* __restrict__ gatb,
                         float* __restrict__ msg_emb, float* __restrict__ msgT,
                         float* __restrict__ cvec) {
    __shared__ float mrow[HIDDEN];
    int b = blockIdx.x;
    int j = threadIdx.x;  // 0..63
    for (int k = j; k < HIDDEN; k += 64) mrow[k] = msg[b * HIDDEN + k];
    __syncthreads();
    float acc = fcb[j];
    #pragma unroll 8
    for (int k = 0; k < HIDDEN; k++) acc += mrow[k] * fcw[k * HOUT + j];
    msg_emb[b * HOUT + j] = acc;
    msgT[j * BATCH + b] = acc;
    float cv = gatb[j] * acc;
    for (int o = 32; o > 0; o >>= 1) cv += __shfl_down(cv, o);
    if (j == 0) cvec[b] = cv;
}

// ---------------- K1: h = x @ gat_w ; a_s, a_d per (node, head)
__global__ void k_node(const float* __restrict__ x, const float* __restrict__ gatw,
                       const float* __restrict__ atts, const float* __restrict__ attd,
                       float* __restrict__ h, float* __restrict__ a_s, float* __restrict__ a_d) {
    int tid = blockIdx.x * blockDim.x + threadIdx.x;
    int n = tid >> 6;
    int j = tid & 63;
    if (n >= N_NODES) return;
    float4 xv = ((const float4*)x)[n];
    float hv = xv.x * gatw[j] + xv.y * gatw[64 + j] + xv.z * gatw[128 + j] + xv.w * gatw[192 + j];
    h[n * 64 + j] = hv;
    float s = hv * atts[j];
    float d = hv * attd[j];
    for (int o = 8; o > 0; o >>= 1) {
        s += __shfl_down(s, o, 16);
        d += __shfl_down(d, o, 16);
    }
    if ((j & 15) == 0) {
        int head = j >> 4;
        a_s[n * 4 + head] = s;
        a_d[n * 4 + head] = d;
    }
}

// ---------------- K2a: count in-degree
__global__ void k_count(const int* __restrict__ ei, int* __restrict__ cnt) {
    int e = blockIdx.x * blockDim.x + threadIdx.x;
    if (e < N_EDGES) atomicAdd(&cnt[ei[N_EDGES + e]], 1);
}

// ---------------- K2b: hierarchical exclusive scan over cnt[50000]
__global__ void k_scan1(const int* __restrict__ cnt, int* __restrict__ localx,
                        int* __restrict__ partial) {
    int b = blockIdx.x, t = threadIdx.x;
    int i = b * 256 + t;
    int v = (i < N_NODES) ? cnt[i] : 0;
    int lane = t & 63, w = t >> 6;
    int sv = v;
    #pragma unroll
    for (int o = 1; o < 64; o <<= 1) {
        int u = __shfl_up(sv, o);
        if (lane >= o) sv += u;
    }
    __shared__ int wsums[4];
    if (lane == 63) wsums[w] = sv;
    __syncthreads();
    int woff = 0;
    #pragma unroll
    for (int k = 0; k < 4; k++) woff += (k < w) ? wsums[k] : 0;
    if (i < N_NODES) localx[i] = woff + sv - v;
    if (t == 0) partial[b] = wsums[0] + wsums[1] + wsums[2] + wsums[3];
}

__global__ void k_scan2(const int* __restrict__ partial, int* __restrict__ blockoff,
                        int* __restrict__ rowptr_last) {
    int t = threadIdx.x;  // 256 threads
    int v = (t < SCAN_NB) ? partial[t] : 0;
    int lane = t & 63, w = t >> 6;
    int sv = v;
    #pragma unroll
    for (int o = 1; o < 64; o <<= 1) {
        int u = __shfl_up(sv, o);
        if (lane >= o) sv += u;
    }
    __shared__ int wsums[4];
    if (lane == 63) wsums[w] = sv;
    __syncthreads();
    int woff = 0;
    #pragma unroll
    for (int k = 0; k < 4; k++) woff += (k < w) ? wsums[k] : 0;
    int excl = woff + sv - v;
    if (t < SCAN_NB) blockoff[t] = excl;
    if (t == 255) rowptr_last[0] = excl + v;  // grand total -> rowptr[N_NODES]
}

__global__ void k_scan3(const int* __restrict__ localx, const int* __restrict__ blockoff,
                        int* __restrict__ rowptr, int* __restrict__ cursor) {
    int i = blockIdx.x * 256 + threadIdx.x;
    if (i < N_NODES) {
        int r = localx[i] + blockoff[blockIdx.x];
        rowptr[i] = r;
        cursor[i] = r;
    }
}

// ---------------- K2c: scatter src indices into CSR slots
__global__ void k_scatter(const int* __restrict__ ei, int* __restrict__ cursor, int* __restrict__ csr) {
    int e = blockIdx.x * blockDim.x + threadIdx.x;
    if (e < N_EDGES) {
        int d = ei[N_EDGES + e];
        int pos = atomicAdd(&cursor[d], 1);
        csr[pos] = ei[e];
    }
}

// ---------------- K3: per-node softmax + aggregation (one wave per node)
// Lane layout for score work: edge = lane>>2, head = lane&3.
// No max-subtraction: |e| <= ~12 so exp is fp32-safe; alpha identical mathematically.
__global__ __launch_bounds__(256, 8) void k_agg(const int* __restrict__ rowptr,
                      const int* __restrict__ csr,
                      const float* __restrict__ a_s, const float* __restrict__ a_d,
                      const float* __restrict__ h, float* __restrict__ agg) {
    __shared__ float salpha[4][64];
    int wid = threadIdx.x >> 6;
    int lane = threadIdx.x & 63;
    int n = blockIdx.x * 4 + wid;
    if (n >= N_NODES) return;
    int beg = rowptr[n], end = rowptr[n + 1];
    int head = lane & 3, eoff = lane >> 2;
    float adh = a_d[n * 4 + head];

    // phase 1: denom = sum exp(e) per head; lanes split 16 edges x 4 heads
    float s = 0.f;
    for (int i = beg + eoff; i < end; i += 16) {
        int src = csr[i];
        s += __expf(lrelu(a_s[src * 4 + head] + adh));
    }
    #pragma unroll
    for (int o = 4; o < 64; o <<= 1) s += __shfl_xor(s, o);
    float inv = 1.f / (s + 1e-16f);

    // phase 2: chunks of 16 edges; each lane computes one alpha, stage in LDS,
    // then lanes = features accumulate with readlane'd src + broadcast alpha.
    float acc = 0.f;
    const float* ap = &salpha[wid][(lane >> 4) * 16];
    for (int base = beg; base < end; base += 16) {
        int e = base + eoff;
        int ec = (e < end) ? e : (end - 1);
        int src = csr[ec];
        float ev = lrelu(a_s[src * 4 + head] + adh);
        float alpha = (e < end) ? __expf(ev) * inv : 0.f;
        salpha[wid][head * 16 + eoff] = alpha;
        __builtin_amdgcn_wave_barrier();
        #pragma unroll
        for (int c = 0; c < 4; c++) {
            float4 av = *(const float4*)(ap + c * 4);
            int s0 = __builtin_amdgcn_readlane(src, c * 16 + 0);
            int s1 = __builtin_amdgcn_readlane(src, c * 16 + 4);
            int s2 = __builtin_amdgcn_readlane(src, c * 16 + 8);
            int s3 = __builtin_amdgcn_readlane(src, c * 16 + 12);
            acc = fmaf(av.x, h[(size_t)s0 * 64 + lane], acc);
            acc = fmaf(av.y, h[(size_t)s1 * 64 + lane], acc);
            acc = fmaf(av.z, h[(size_t)s2 * 64 + lane], acc);
            acc = fmaf(av.w, h[(size_t)s3 * 64 + lane], acc);
        }
        __builtin_amdgcn_wave_barrier();
    }
    agg[(size_t)n * 64 + lane] = acc;
}

// ---------------- K3b: transpose agg [N][64] -> aggT [64][ATS]
__global__ void k_transpose(const float* __restrict__ agg, float* __restrict__ aggT) {
    __shared__ float tile[64][65];
    int t = threadIdx.x;
    int n0 = blockIdx.x * 64;
    #pragma unroll
    for (int i = 0; i < 16; i++) {
        int idx = i * 256 + t;
        int nl = idx >> 6, f = idx & 63;
        int n = n0 + nl;
        tile[nl][f] = (n < N_NODES) ? agg[(size_t)n * 64 + f] : 0.f;
    }
    __syncthreads();
    #pragma unroll
    for (int i = 0; i < 16; i++) {
        int idx = i * 256 + t;
        int f = idx >> 6, nl = idx & 63;
        int n = n0 + nl;
        if (n < N_NODES) aggT[(size_t)f * ATS + n] = tile[nl][f];
    }
}

// ---------------- K4: logits = aggT^T @ msg_emb^T + c[b]; coalesced, scalar-path B operand
__global__ __launch_bounds__(256, 4) void k_logits(const float* __restrict__ aggT,
    const float* __restrict__ msgT, const float* __restrict__ cvec,
    float* __restrict__ out, float* __restrict__ pm, float* __restrict__ ps) {
    __shared__ float red_m[16][4], red_s[16][4];
    int t = threadIdx.x;
    int bg = blockIdx.x;     // 0..63 : 16 batch rows each
    int chunk = blockIdx.y;  // 0..48 : 1024 nodes each
    int nbase = chunk * 1024;
    float acc[4][16];
    #pragma unroll
    for (int s = 0; s < 4; s++)
        #pragma unroll
        for (int b = 0; b < 16; b++) acc[s][b] = 0.f;

    #pragma unroll 2
    for (int k = 0; k < 64; k++) {
        float aR[4];
        #pragma unroll
        for (int s = 0; s < 4; s++)
            aR[s] = aggT[(size_t)k * ATS + nbase + s * 256 + t];
        const float* mrow = msgT + k * BATCH + bg * 16;  // wave-uniform -> s_load
        #pragma unroll
        for (int b = 0; b < 16; b++) {
            float m = mrow[b];
            #pragma unroll
            for (int s = 0; s < 4; s++) acc[s][b] = fmaf(aR[s], m, acc[s][b]);
        }
    }

    int lane = t & 63, w = t >> 6;
    #pragma unroll
    for (int b = 0; b < 16; b++) {
        int bglob = bg * 16 + b;
        float sc = cvec[bglob];
        float lm = -INFINITY, ls = 0.f;
        #pragma unroll
        for (int s = 0; s < 4; s++) {
            int n = nbase + s * 256 + t;
            if (n < N_NODES) {
                float lv = acc[s][b] + sc;
                out[(size_t)bglob * N_NODES + n] = lv;
                if (lv > lm) { ls = ls * __expf(lm - lv) + 1.f; lm = lv; }
                else ls += __expf(lv - lm);
            }
        }
        #pragma unroll
        for (int o = 1; o < 64; o <<= 1) {
            float mo = __shfl_xor(lm, o), so = __shfl_xor(ls, o);
            float M = fmaxf(lm, mo);
            float t1 = (ls == 0.f) ? 0.f : ls * __expf(lm - M);
            float t2 = (so == 0.f) ? 0.f : so * __expf(mo - M);
            lm = M; ls = t1 + t2;
        }
        if (lane == 0) { red_m[b][w] = lm; red_s[b][w] = ls; }
    }
    __syncthreads();
    if (t < 16) {
        float M = -INFINITY;
        #pragma unroll
        for (int i = 0; i < 4; i++) M = fmaxf(M, red_m[t][i]);
        float S = 0.f;
        #pragma unroll
        for (int i = 0; i < 4; i++)
            S += (red_s[t][i] == 0.f) ? 0.f : red_s[t][i] * __expf(red_m[t][i] - M);
        pm[(bg * 16 + t) * NCHUNK + chunk] = M;
        ps[(bg * 16 + t) * NCHUNK + chunk] = S;
    }
}

// ---------------- K5: combine partials per batch row
__global__ void k_rowstats(const float* __restrict__ pm, const float* __restrict__ ps,
                           float* __restrict__ rowm, float* __restrict__ rowls) {
    int b = blockIdx.x * blockDim.x + threadIdx.x;
    if (b >= BATCH) return;
    float M = -INFINITY;
    for (int i = 0; i < NCHUNK; i++) M = fmaxf(M, pm[b * NCHUNK + i]);
    float S = 0.f;
    for (int i = 0; i < NCHUNK; i++) {
        float s = ps[b * NCHUNK + i];
        S += (s == 0.f) ? 0.f : s * __expf(pm[b * NCHUNK + i] - M);
    }
    rowm[b] = M;
    rowls[b] = logf(S);
}

// ---------------- K6: out = logits - (M + log S)
__global__ void k_fix(float* __restrict__ out, const float* __restrict__ rowm,
                      const float* __restrict__ rowls) {
    int idx = blockIdx.x * blockDim.x + threadIdx.x;  // float4 index
    int b = idx / 12500;                              // 50000/4 float4 per row
    float sub = rowm[b] + rowls[b];
    float4 v = ((float4*)out)[idx];
    v.x -= sub; v.y -= sub; v.z -= sub; v.w -= sub;
    ((float4*)out)[idx] = v;
}

extern "C" void kernel_launch(void* const* d_in, const int* in_sizes, int n_in,
                              void* d_out, int out_size, void* d_ws, size_t ws_size,
                              hipStream_t stream) {
    const float* message = (const float*)d_in[0];
    const float* x       = (const float*)d_in[1];
    const int*   ei      = (const int*)d_in[2];
    const float* gat_w   = (const float*)d_in[3];
    const float* att_src = (const float*)d_in[4];
    const float* att_dst = (const float*)d_in[5];
    const float* gat_b   = (const float*)d_in[6];
    const float* fc_w    = (const float*)d_in[7];
    const float* fc_b    = (const float*)d_in[8];
    float* out = (float*)d_out;

    float* ws      = (float*)d_ws;
    float* msg_emb = ws;                               // 1024*64
    float* msgT    = msg_emb + BATCH * HOUT;           // 64*1024
    float* cvec    = msgT + HOUT * BATCH;              // 1024
    float* a_s     = cvec + BATCH;                     // 50000*4
    float* a_d     = a_s + (size_t)N_NODES * HEADS;    // 50000*4
    float* agg     = a_d + (size_t)N_NODES * HEADS;    // 50000*64
    float* hbuf    = agg + (size_t)N_NODES * HOUT;     // h then aggT (aliased)
    float* aggT    = hbuf;
    float* pm      = hbuf + (size_t)HOUT * ATS;        // 1024*49
    float* ps      = pm + BATCH * NCHUNK;              // 1024*49
    float* rowm    = ps + BATCH * NCHUNK;              // 1024
    float* rowls   = rowm + BATCH;                     // 1024
    int*   cnt     = (int*)(rowls + BATCH);            // 50000
    int*   rowptr  = cnt + N_NODES;                    // 50001
    int*   cursor  = rowptr + N_NODES + 1;             // 50000
    int*   csr     = cursor + N_NODES;                 // 1600000
    int*   localx  = csr + N_EDGES;                    // 50000
    int*   partial = localx + N_NODES;                 // 196
    int*   blockoff= partial + SCAN_NB;                // 196

    hipMemsetAsync(cnt, 0, N_NODES * sizeof(int), stream);
    k_msgemb<<<BATCH, 64, 0, stream>>>(message, fc_w, fc_b, gat_b, msg_emb, msgT, cvec);
    k_node<<<(N_NODES * 64 + 255) / 256, 256, 0, stream>>>(x, gat_w, att_src, att_dst, hbuf, a_s, a_d);
    k_count<<<N_EDGES / 256, 256, 0, stream>>>(ei, cnt);
    k_scan1<<<SCAN_NB, 256, 0, stream>>>(cnt, localx, partial);
    k_scan2<<<1, 256, 0, stream>>>(partial, blockoff, rowptr + N_NODES);
    k_scan3<<<SCAN_NB, 256, 0, stream>>>(localx, blockoff, rowptr, cursor);
    k_scatter<<<N_EDGES / 256, 256, 0, stream>>>(ei, cursor, csr);
    k_agg<<<(N_NODES + 3) / 4, 256, 0, stream>>>(rowptr, csr, a_s, a_d, hbuf, agg);
    k_transpose<<<(N_NODES + 63) / 64, 256, 0, stream>>>(agg, aggT);
    dim3 g4(64, NCHUNK);
    k_logits<<<g4, 256, 0, stream>>>(aggT, msgT, cvec, out, pm, ps);
    k_rowstats<<<4, 256, 0, stream>>>(pm, ps, rowm, rowls);
    k_fix<<<(BATCH * N_NODES / 4 + 255) / 256, 256, 0, stream>>>(out, rowm, rowls);
}